// Round 12
// baseline (1293.174 us; speedup 1.0000x reference)
//
#include <hip/hip_runtime.h>
#include <math.h>

#define N_NODES 100000
#define N_EDGES 500000
#define N_PATHS 3
#define DIM 128
#define K_LAYERS 10
#define NBLK_PER_PATH ((N_NODES + 255) / 256)   // 391
#define PN (N_PATHS * N_NODES)                  // 300000
#define HRANGE 8192                             // LDS histogram bins (32 KB)
#define NRANGE ((N_NODES + HRANGE - 1) / HRANGE) // 13
#define BPG 16                                  // blocks per histogram group
#define NBUCKET 64                              // degree buckets for node sort

typedef __attribute__((ext_vector_type(8))) short bf16x8;
typedef __attribute__((ext_vector_type(4))) float f32x4;

__device__ __forceinline__ float bflo(unsigned u) { return __uint_as_float(u << 16); }
__device__ __forceinline__ float bfhi(unsigned u) { return __uint_as_float(u & 0xffff0000u); }

// ---------------- degree histograms via LDS privatization -----------------------
__global__ __launch_bounds__(256) void hist_kernel(const int* __restrict__ edges,
                                                   int* __restrict__ partial) {
    __shared__ int hist[HRANGE];
    int g = blockIdx.x / BPG;
    int b = blockIdx.x - g * BPG;
    int r = g % NRANGE;
    int pt = g / NRANGE;           // p*2 + t
    int p = pt >> 1, t = pt & 1;
    for (int i = threadIdx.x; i < HRANGE; i += 256) hist[i] = 0;
    __syncthreads();

    const int4* arr4 = (const int4*)(edges + ((size_t)p * 2 + t) * N_EDGES);
    const int n4 = N_EDGES / 4;
    const int stride = BPG * 256;
    int lo = r * HRANGE;

    int i4 = b * 256 + threadIdx.x;
    int4 cur = make_int4(-1, -1, -1, -1);
    if (i4 < n4) cur = arr4[i4];
    while (i4 < n4) {
        int ni = i4 + stride;
        int4 nxt = make_int4(-1, -1, -1, -1);
        if (ni < n4) nxt = arr4[ni];           // prefetch in flight during processing
        int v0 = cur.x - lo, v1 = cur.y - lo, v2 = cur.z - lo, v3 = cur.w - lo;
        if ((unsigned)v0 < HRANGE) atomicAdd(&hist[v0], 1);
        if ((unsigned)v1 < HRANGE) atomicAdd(&hist[v1], 1);
        if ((unsigned)v2 < HRANGE) atomicAdd(&hist[v2], 1);
        if ((unsigned)v3 < HRANGE) atomicAdd(&hist[v3], 1);
        cur = nxt;
        i4 = ni;
    }
    __syncthreads();
    int* outp = partial + ((size_t)g * BPG + b) * HRANGE;
    for (int i = threadIdx.x; i < HRANGE; i += 256) outp[i] = hist[i];
}

// ---------------- reduce partials -> norms + total in-degree ----------------
__global__ __launch_bounds__(256) void deg_reduce_kernel(const int* __restrict__ partial,
                                                         float* __restrict__ norm_s,
                                                         float* __restrict__ norm_d,
                                                         int* __restrict__ degD_tot) {
    int i = blockIdx.x * 256 + threadIdx.x;
    if (i >= PN) return;
    int p = i / N_NODES, n = i - p * N_NODES;
    int r = n / HRANGE, off = n - r * HRANGE;
    const int* ps = partial + (((size_t)(p * 2 + 0) * NRANGE + r) * BPG) * HRANGE + off;
    const int* pd = partial + (((size_t)(p * 2 + 1) * NRANGE + r) * BPG) * HRANGE + off;
    int sS = 0, sD = 0;
#pragma unroll
    for (int b = 0; b < BPG; ++b) {
        sS += ps[(size_t)b * HRANGE];
        sD += pd[(size_t)b * HRANGE];
    }
    norm_s[i] = 1.0f / sqrtf(fmaxf((float)sS, 1.0f));
    norm_d[i] = 1.0f / sqrtf(fmaxf((float)sD, 1.0f));
    degD_tot[i] = sD;
}

// ---------------- degree-bucket histogram (3 paths x 64 buckets) ----------------
__global__ __launch_bounds__(256) void bhist_kernel(const int* __restrict__ degD_tot,
                                                    int* __restrict__ bcount) {
    __shared__ int h[3 * NBUCKET];
    for (int i = threadIdx.x; i < 3 * NBUCKET; i += 256) h[i] = 0;
    __syncthreads();
    int i = blockIdx.x * 256 + threadIdx.x;
    if (i < PN) {
        int p = i / N_NODES;
        int b = min(degD_tot[i], NBUCKET - 1);
        atomicAdd(&h[p * NBUCKET + b], 1);
    }
    __syncthreads();
    for (int i2 = threadIdx.x; i2 < 3 * NBUCKET; i2 += 256)
        if (h[i2]) atomicAdd(&bcount[i2], h[i2]);
}

// ---------------- exclusive scan of buckets within each path (1 block) ----------
__global__ void bscan_kernel(const int* __restrict__ bcount, int* __restrict__ bcursor) {
    __shared__ int s[3 * NBUCKET];
    int t = threadIdx.x;                 // 0..191
    int v = bcount[t];
    s[t] = v;
    __syncthreads();
    for (int off = 1; off < NBUCKET; off <<= 1) {
        int x = s[t];
        int add = ((t & (NBUCKET - 1)) >= off) ? s[t - off] : 0;
        __syncthreads();
        s[t] = x + add;
        __syncthreads();
    }
    bcursor[t] = s[t] - v;               // exclusive within path
}

// ---------------- scatter nodes into degree-sorted perm -------------------------
// LDS local ranking + one global atomic per (block, touched bucket).
__global__ __launch_bounds__(256) void bscatter_kernel(const int* __restrict__ degD_tot,
                                                       int* __restrict__ bcursor,
                                                       int* __restrict__ perm) {
    __shared__ int h[3 * NBUCKET];
    __shared__ int base[3 * NBUCKET];
    for (int i = threadIdx.x; i < 3 * NBUCKET; i += 256) h[i] = 0;
    __syncthreads();
    int i = blockIdx.x * 256 + threadIdx.x;
    int p = 0, n = 0, bk = 0, rank = 0;
    bool act = i < PN;
    if (act) {
        p = i / N_NODES;
        n = i - p * N_NODES;
        bk = min(degD_tot[i], NBUCKET - 1);
        rank = atomicAdd(&h[p * NBUCKET + bk], 1);
    }
    __syncthreads();
    for (int i2 = threadIdx.x; i2 < 3 * NBUCKET; i2 += 256) {
        int c = h[i2];
        base[i2] = c ? atomicAdd(&bcursor[i2], c) : 0;
    }
    __syncthreads();
    if (act) perm[p * N_NODES + base[p * NBUCKET + bk] + rank] = n;
}

// ---------------- hierarchical scan: phase A - per-block sums ----------------
__global__ __launch_bounds__(256) void blocksum_kernel(const int* __restrict__ cnt,
                                                       int* __restrict__ bsum) {
    int b = blockIdx.x;
    int p = b / NBLK_PER_PATH;
    int lb = b - p * NBLK_PER_PATH;
    int idx = lb * 256 + threadIdx.x;
    int v = (idx < N_NODES) ? cnt[p * N_NODES + idx] : 0;
#pragma unroll
    for (int off = 32; off; off >>= 1) v += __shfl_xor(v, off);
    __shared__ int ws[4];
    if ((threadIdx.x & 63) == 0) ws[threadIdx.x >> 6] = v;
    __syncthreads();
    if (threadIdx.x == 0) bsum[b] = ws[0] + ws[1] + ws[2] + ws[3];
}

// ---------------- phase B - scan the 391 block sums per path --------
__global__ __launch_bounds__(512) void pscan_kernel(int* __restrict__ bsum) {
    __shared__ int s[512];
    int p = blockIdx.x;
    int t = threadIdx.x;
    int v = (t < NBLK_PER_PATH) ? bsum[p * NBLK_PER_PATH + t] : 0;
    s[t] = v;
    __syncthreads();
    for (int off = 1; off < 512; off <<= 1) {
        int x = s[t];
        int a = (t >= off) ? s[t - off] : 0;
        __syncthreads();
        s[t] = x + a;
        __syncthreads();
    }
    if (t < NBLK_PER_PATH) bsum[p * NBLK_PER_PATH + t] = s[t] - v;   // exclusive
}

// ---------------- phase C - block-local rescan + write row_ptr/cursor ----------
__global__ __launch_bounds__(256) void scan_write_kernel(const int* __restrict__ cnt,
                                                         const int* __restrict__ bsum,
                                                         int* __restrict__ row_ptr_all,
                                                         int* __restrict__ cursor_all) {
    __shared__ int s[256];
    int b = blockIdx.x;
    int p = b / NBLK_PER_PATH;
    int lb = b - p * NBLK_PER_PATH;
    int idx = lb * 256 + threadIdx.x;
    int t = threadIdx.x;
    int v = (idx < N_NODES) ? cnt[p * N_NODES + idx] : 0;
    s[t] = v;
    __syncthreads();
    for (int off = 1; off < 256; off <<= 1) {
        int x = s[t];
        int a = (t >= off) ? s[t - off] : 0;
        __syncthreads();
        s[t] = x + a;
        __syncthreads();
    }
    int excl = s[t] - v + bsum[b];
    if (idx < N_NODES) {
        row_ptr_all[p * (N_NODES + 1) + idx] = excl;
        cursor_all[p * N_NODES + idx] = excl;
        if (idx == N_NODES - 1)
            row_ptr_all[p * (N_NODES + 1) + N_NODES] = excl + v;
    }
}

// ---------------- fill CSR: col=src, weight=0.9*norm_s[src]*norm_d[dst] --------
__global__ __launch_bounds__(256) void fill_kernel(const int* __restrict__ edges,
                                                   const float* __restrict__ norm_s,
                                                   const float* __restrict__ norm_d,
                                                   int* __restrict__ cursor,
                                                   int2* __restrict__ cw) {
    int idx = blockIdx.x * 256 + threadIdx.x;
    if (idx < N_PATHS * N_EDGES) {
        int p = idx / N_EDGES;
        int e = idx - p * N_EDGES;
        const int* src = edges + (size_t)p * 2 * N_EDGES;
        const int* dst = src + N_EDGES;
        int s = src[e], d = dst[e];
        int pos = atomicAdd(&cursor[p * N_NODES + d], 1);
        float w = 0.9f * norm_s[p * N_NODES + s] * norm_d[p * N_NODES + d];
        cw[(size_t)p * N_EDGES + pos] = make_int2(s, __float_as_int(w));
    }
}

__device__ __forceinline__ unsigned bf16pack(float a, float b) {
    unsigned ua = __float_as_uint(a), ub = __float_as_uint(b);
    ua = (ua + 0x7fffu + ((ua >> 16) & 1)) >> 16;
    ub = (ub + 0x7fffu + ((ub >> 16) & 1)) >> 16;
    return ua | (ub << 16);
}

// ---------------- f32 -> bf16 cast of h (once) ----------------
__global__ __launch_bounds__(256) void cast_kernel(const float4* __restrict__ in,
                                                   ushort4* __restrict__ outp) {
    int idx = blockIdx.x * 256 + threadIdx.x;
    if (idx < N_NODES * DIM / 4) {
        float4 v = in[idx];
        ushort4 o;
        unsigned u;
        u = __float_as_uint(v.x); o.x = (unsigned short)((u + 0x7fff + ((u >> 16) & 1)) >> 16);
        u = __float_as_uint(v.y); o.y = (unsigned short)((u + 0x7fff + ((u >> 16) & 1)) >> 16);
        u = __float_as_uint(v.z); o.z = (unsigned short)((u + 0x7fff + ((u >> 16) & 1)) >> 16);
        u = __float_as_uint(v.w); o.w = (unsigned short)((u + 0x7fff + ((u >> 16) & 1)) >> 16);
        outp[idx] = o;
    }
}

// ---------------- W1^T bf16 (128x128, once) ----------------
__global__ __launch_bounds__(256) void w1t_kernel(const float* __restrict__ W1,
                                                  unsigned short* __restrict__ W1t) {
    int idx = blockIdx.x * 256 + threadIdx.x;
    if (idx < DIM * DIM) {
        int c = idx >> 7, k = idx & 127;     // W1t[c][k] = bf16(W1[k][c])
        unsigned u = __float_as_uint(W1[k * DIM + c]);
        W1t[idx] = (unsigned short)((u + 0x7fff + ((u >> 16) & 1)) >> 16);
    }
}

// ---------------- one APPNP layer, bf16 state, octet-wave, degree-sorted --------
// perm groups equal-degree nodes into each wave -> maxd == deg (no masked-
// iteration waste). Per-node math identical to unsorted (bitwise).
template <int OUT_F32, int H_BF16>
__global__ __launch_bounds__(256) void prop_kernel(const unsigned short* __restrict__ xin,
                                                   size_t in_stride,    // elems per path (0 = shared)
                                                   const void* __restrict__ anchor,
                                                   void* __restrict__ xout,
                                                   const int* __restrict__ row_ptr,
                                                   const int2* __restrict__ cw,
                                                   const int* __restrict__ perm) {
    int wid  = threadIdx.x >> 6;
    int lane = threadIdx.x & 63;
    int oct  = lane >> 3;          // node slot 0..7
    int ol   = lane & 7;           // uint4 column (covers ol and ol+8)
    int nodeBase = blockIdx.x * 32 + wid * 8;    // wave-uniform; one path per wave
    int p  = nodeBase / N_NODES;
    int nb = nodeBase - p * N_NODES;
    const int*  rp   = row_ptr + p * (N_NODES + 1);
    const int2* cwp  = cw + (size_t)p * N_EDGES;
    const int*  pmp  = perm + p * N_NODES;
    const uint4* xin4 = (const uint4*)(xin + (size_t)p * in_stride);

    int pidx = (lane < 16) ? pmp[nb + (lane & 7)] : 0;
    int rv   = (lane < 16) ? rp[pidx + (lane >> 3)] : 0;  // lanes 0-7: beg, 8-15: end
    int beg = __shfl(rv, oct);
    int end = __shfl(rv, oct + 8);
    int deg = end - beg;
    int myNode = __shfl(pidx, oct);
    int maxd = deg;
    maxd = max(maxd, __shfl_xor(maxd, 8));
    maxd = max(maxd, __shfl_xor(maxd, 16));
    maxd = max(maxd, __shfl_xor(maxd, 32));

    float a0 = 0.f, a1 = 0.f, a2 = 0.f, a3 = 0.f;
    float a4 = 0.f, a5 = 0.f, a6 = 0.f, a7 = 0.f;
    float a8 = 0.f, a9 = 0.f, a10 = 0.f, a11 = 0.f;
    float a12 = 0.f, a13 = 0.f, a14 = 0.f, a15 = 0.f;

    for (int base = 0; base < maxd; base += 8) {
        int2 e = make_int2(0, 0);
        if (base + ol < deg) e = cwp[beg + base + ol];   // 8 edge records per node
        int lim = maxd - base; if (lim > 8) lim = 8;
#pragma unroll 4
        for (int j = 0; j < lim; ++j) {
            int lsrc = (lane & 56) | j;
            int   c = __shfl(e.x, lsrc);
            float w = __int_as_float(__shfl(e.y, lsrc));
            if (base + j < deg) {      // oct-uniform exec mask (rarely divergent now)
                uint4 v1 = xin4[(size_t)c * 16 + ol];
                uint4 v2 = xin4[(size_t)c * 16 + 8 + ol];
                a0  = fmaf(w, bflo(v1.x), a0);  a1  = fmaf(w, bfhi(v1.x), a1);
                a2  = fmaf(w, bflo(v1.y), a2);  a3  = fmaf(w, bfhi(v1.y), a3);
                a4  = fmaf(w, bflo(v1.z), a4);  a5  = fmaf(w, bfhi(v1.z), a5);
                a6  = fmaf(w, bflo(v1.w), a6);  a7  = fmaf(w, bfhi(v1.w), a7);
                a8  = fmaf(w, bflo(v2.x), a8);  a9  = fmaf(w, bfhi(v2.x), a9);
                a10 = fmaf(w, bflo(v2.y), a10); a11 = fmaf(w, bfhi(v2.y), a11);
                a12 = fmaf(w, bflo(v2.z), a12); a13 = fmaf(w, bfhi(v2.z), a13);
                a14 = fmaf(w, bflo(v2.w), a14); a15 = fmaf(w, bfhi(v2.w), a15);
            }
        }
    }

    if (H_BF16) {
        uint4 hv1 = ((const uint4*)anchor)[(size_t)myNode * 16 + ol];
        uint4 hv2 = ((const uint4*)anchor)[(size_t)myNode * 16 + 8 + ol];
        a0  += 0.1f * bflo(hv1.x); a1  += 0.1f * bfhi(hv1.x);
        a2  += 0.1f * bflo(hv1.y); a3  += 0.1f * bfhi(hv1.y);
        a4  += 0.1f * bflo(hv1.z); a5  += 0.1f * bfhi(hv1.z);
        a6  += 0.1f * bflo(hv1.w); a7  += 0.1f * bfhi(hv1.w);
        a8  += 0.1f * bflo(hv2.x); a9  += 0.1f * bfhi(hv2.x);
        a10 += 0.1f * bflo(hv2.y); a11 += 0.1f * bfhi(hv2.y);
        a12 += 0.1f * bflo(hv2.z); a13 += 0.1f * bfhi(hv2.z);
        a14 += 0.1f * bflo(hv2.w); a15 += 0.1f * bfhi(hv2.w);
    } else {
        const float4* h4 = (const float4*)anchor + (size_t)myNode * 32;
        float4 p0 = h4[ol * 2], p1 = h4[ol * 2 + 1];
        float4 p2 = h4[ol * 2 + 16], p3 = h4[ol * 2 + 17];
        a0  += 0.1f * p0.x; a1  += 0.1f * p0.y; a2  += 0.1f * p0.z; a3  += 0.1f * p0.w;
        a4  += 0.1f * p1.x; a5  += 0.1f * p1.y; a6  += 0.1f * p1.z; a7  += 0.1f * p1.w;
        a8  += 0.1f * p2.x; a9  += 0.1f * p2.y; a10 += 0.1f * p2.z; a11 += 0.1f * p2.w;
        a12 += 0.1f * p3.x; a13 += 0.1f * p3.y; a14 += 0.1f * p3.z; a15 += 0.1f * p3.w;
    }

    size_t row = (size_t)p * N_NODES + myNode;
    if (OUT_F32) {
        float4* zo = (float4*)xout + row * 32;
        zo[ol * 2]      = make_float4(a0, a1, a2, a3);
        zo[ol * 2 + 1]  = make_float4(a4, a5, a6, a7);
        zo[ol * 2 + 16] = make_float4(a8, a9, a10, a11);
        zo[ol * 2 + 17] = make_float4(a12, a13, a14, a15);
    } else {
        uint4 o1, o2;
        o1.x = bf16pack(a0, a1);   o1.y = bf16pack(a2, a3);
        o1.z = bf16pack(a4, a5);   o1.w = bf16pack(a6, a7);
        o2.x = bf16pack(a8, a9);   o2.y = bf16pack(a10, a11);
        o2.z = bf16pack(a12, a13); o2.w = bf16pack(a14, a15);
        ((uint4*)xout)[row * 16 + ol]     = o1;
        ((uint4*)xout)[row * 16 + 8 + ol] = o2;
    }
}

__device__ __forceinline__ float fast_tanh(float x) {
    float e = __expf(2.0f * x);
    return 1.0f - 2.0f / (e + 1.0f);   // == (e-1)/(e+1) == tanh(x)
}

// ---------------- attention logits via MFMA ----------------
__global__ __launch_bounds__(256) void attn_kernel(const float* __restrict__ z,
                                                   const unsigned short* __restrict__ W1t,
                                                   const float* __restrict__ b1,
                                                   const float* __restrict__ w2,
                                                   float* __restrict__ wsum) {
    const int wid  = threadIdx.x >> 6;
    const int lane = threadIdx.x & 63;
    const int c0   = lane & 15;
    const int kh   = lane >> 4;

    const bf16x8* w1t8 = (const bf16x8*)W1t;
    bf16x8 Bf[8][4];
#pragma unroll
    for (int nt = 0; nt < 8; ++nt)
#pragma unroll
        for (int ks = 0; ks < 4; ++ks)
            Bf[nt][ks] = w1t8[(nt * 16 + c0) * 16 + ks * 4 + kh];

    float b1v[8], w2v[8];
#pragma unroll
    for (int nt = 0; nt < 8; ++nt) {
        b1v[nt] = b1[nt * 16 + c0];
        w2v[nt] = w2[nt * 16 + c0];
    }

    float accP0 = 0.f, accP1 = 0.f, accP2 = 0.f;
    const int NTILES = N_PATHS * N_NODES / 16;   // 18750
    const int TPP    = N_NODES / 16;             // 6250
    const int stride = gridDim.x * 4;
    const float4* zf4 = (const float4*)z;

    for (int t = blockIdx.x * 4 + wid; t < NTILES; t += stride) {
        size_t rbase = ((size_t)t * 16 + c0) * 32 + kh * 2;
        bf16x8 Af[4];
#pragma unroll
        for (int ks = 0; ks < 4; ++ks) {
            float4 x0 = zf4[rbase + ks * 8];
            float4 x1 = zf4[rbase + ks * 8 + 1];
            union { uint4 u; bf16x8 v; } cv;
            cv.u.x = bf16pack(x0.x, x0.y);
            cv.u.y = bf16pack(x0.z, x0.w);
            cv.u.z = bf16pack(x1.x, x1.y);
            cv.u.w = bf16pack(x1.z, x1.w);
            Af[ks] = cv.v;
        }
        f32x4 acc[8];
#pragma unroll
        for (int nt = 0; nt < 8; ++nt) acc[nt] = (f32x4){0.f, 0.f, 0.f, 0.f};
#pragma unroll
        for (int nt = 0; nt < 8; ++nt)
#pragma unroll
            for (int ks = 0; ks < 4; ++ks)
                acc[nt] = __builtin_amdgcn_mfma_f32_16x16x32_bf16(Af[ks], Bf[nt][ks], acc[nt], 0, 0, 0);

        float psum = 0.f;
#pragma unroll
        for (int nt = 0; nt < 8; ++nt) {
            psum += fast_tanh(acc[nt][0] + b1v[nt]) * w2v[nt];
            psum += fast_tanh(acc[nt][1] + b1v[nt]) * w2v[nt];
            psum += fast_tanh(acc[nt][2] + b1v[nt]) * w2v[nt];
            psum += fast_tanh(acc[nt][3] + b1v[nt]) * w2v[nt];
        }
#pragma unroll
        for (int off = 32; off; off >>= 1) psum += __shfl_xor(psum, off);
        if (lane == 0) {
            int p = t / TPP;
            if (p == 0) accP0 += psum;
            else if (p == 1) accP1 += psum;
            else accP2 += psum;
        }
    }
    if (lane == 0) {
        if (accP0 != 0.f) atomicAdd(&wsum[0], accP0);
        if (accP1 != 0.f) atomicAdd(&wsum[1], accP1);
        if (accP2 != 0.f) atomicAdd(&wsum[2], accP2);
    }
}

// ---------------- beta = softmax(wsum / N) over 3 paths ----------------
__global__ void beta_kernel(const float* __restrict__ wsum, float* __restrict__ beta) {
    if (threadIdx.x == 0 && blockIdx.x == 0) {
        float w0 = wsum[0] * (1.0f / N_NODES);
        float w1 = wsum[1] * (1.0f / N_NODES);
        float w2v = wsum[2] * (1.0f / N_NODES);
        float m = fmaxf(w0, fmaxf(w1, w2v));
        float e0 = expf(w0 - m), e1 = expf(w1 - m), e2 = expf(w2v - m);
        float inv = 1.0f / (e0 + e1 + e2);
        beta[0] = e0 * inv;
        beta[1] = e1 * inv;
        beta[2] = e2 * inv;
    }
}

// ---------------- out[n,:] = sum_p beta[p] * z[p,n,:] ----------------
__global__ __launch_bounds__(256) void combine_kernel(const float4* __restrict__ z4,
                                                      const float* __restrict__ beta,
                                                      float4* __restrict__ out4) {
    size_t idx = (size_t)blockIdx.x * 256 + threadIdx.x;
    const size_t M = (size_t)N_NODES * 32;
    if (idx < M) {
        float b0 = beta[0], b1 = beta[1], b2 = beta[2];
        float4 a = z4[idx];
        float4 b = z4[M + idx];
        float4 c = z4[2 * M + idx];
        float4 o;
        o.x = b0 * a.x + b1 * b.x + b2 * c.x;
        o.y = b0 * a.y + b1 * b.y + b2 * c.y;
        o.z = b0 * a.z + b1 * b.z + b2 * c.z;
        o.w = b0 * a.w + b1 * b.w + b2 * c.w;
        out4[idx] = o;
    }
}

extern "C" void kernel_launch(void* const* d_in, const int* in_sizes, int n_in,
                              void* d_out, int out_size, void* d_ws, size_t ws_size,
                              hipStream_t stream) {
    const float* h     = (const float*)d_in[0];
    const int*   edges = (const int*)d_in[1];   // (3, 2, 500000) int32
    const float* W1    = (const float*)d_in[2];
    const float* b1    = (const float*)d_in[3];
    const float* w2    = (const float*)d_in[4];
    float* out = (float*)d_out;

    // ---- workspace carve ----
    char* ws = (char*)d_ws;
    float* z = (float*)ws;               ws += (size_t)N_PATHS * N_NODES * DIM * 4;  // 153.6 MB
    unsigned short* buf0 = (unsigned short*)ws; ws += (size_t)N_PATHS * N_NODES * DIM * 2;  // 76.8 MB
    int2* cw = (int2*)ws;                ws += (size_t)N_PATHS * N_EDGES * 8;        // 12 MB
    int* row_ptr = (int*)ws;             ws += (size_t)N_PATHS * (N_NODES + 1) * 4 + 12;
    float* norm_s = (float*)ws;          ws += (size_t)PN * 4;
    float* norm_d = (float*)ws;          ws += (size_t)PN * 4;
    int* bsum = (int*)ws;                ws += (size_t)N_PATHS * NBLK_PER_PATH * 4;
    float* wsum = (float*)ws;            ws += 4 * 4;
    float* beta = (float*)ws;            ws += 4 * 4;
    unsigned short* W1t = (unsigned short*)ws; ws += (size_t)DIM * DIM * 2;          // 32 KB
    int* perm = (int*)ws;                ws += (size_t)PN * 4;                       // 1.2 MB (lives through prop)
    int* bcount = (int*)ws;              ws += 3 * NBUCKET * 4;
    int* bcursor = (int*)ws;             ws += 3 * NBUCKET * 4;
    // CSR-build temporaries inside buf0 (dead until prop layer 0 writes it):
    int* partial  = (int*)buf0;                               // 40.9 MB
    int* degD_tot = partial + (size_t)3 * 2 * NRANGE * BPG * HRANGE;  // 1.2 MB
    int* cursor   = degD_tot + PN;                            // 1.2 MB
    // aliases inside z (dead before layer 9 writes z):
    unsigned short* buf1 = (unsigned short*)z;                                   // 76.8 MB
    unsigned short* hb   = (unsigned short*)z + (size_t)N_PATHS * N_NODES * DIM; // 25.6 MB

    const size_t PSTRIDE = (size_t)N_NODES * DIM;   // per-path elems

    // ---- CSR build ----
    hist_kernel<<<3 * 2 * NRANGE * BPG, 256, 0, stream>>>(edges, partial);
    deg_reduce_kernel<<<(PN + 255) / 256, 256, 0, stream>>>(partial, norm_s, norm_d, degD_tot);
    // degree-sorted node permutation (counting sort by in-degree bucket)
    hipMemsetAsync(bcount, 0, 3 * NBUCKET * 4, stream);
    bhist_kernel<<<(PN + 255) / 256, 256, 0, stream>>>(degD_tot, bcount);
    bscan_kernel<<<1, 3 * NBUCKET, 0, stream>>>(bcount, bcursor);
    bscatter_kernel<<<(PN + 255) / 256, 256, 0, stream>>>(degD_tot, bcursor, perm);
    // row_ptr + cursor
    blocksum_kernel<<<N_PATHS * NBLK_PER_PATH, 256, 0, stream>>>(degD_tot, bsum);
    pscan_kernel<<<N_PATHS, 512, 0, stream>>>(bsum);
    scan_write_kernel<<<N_PATHS * NBLK_PER_PATH, 256, 0, stream>>>(degD_tot, bsum, row_ptr, cursor);
    fill_kernel<<<(N_PATHS * N_EDGES + 255) / 256, 256, 0, stream>>>(edges, norm_s, norm_d, cursor, cw);

    // ---- one-time casts ----
    cast_kernel<<<(N_NODES * DIM / 4 + 255) / 256, 256, 0, stream>>>(
        (const float4*)h, (ushort4*)hb);
    w1t_kernel<<<(DIM * DIM + 255) / 256, 256, 0, stream>>>(W1, W1t);

    // ---- APPNP propagation: 10 fused layers over all 3 paths ----
    const int pgrid = PN / 32;   // 9375 blocks, 8 nodes/wave
    prop_kernel<0, 1><<<pgrid, 256, 0, stream>>>(hb, 0, hb, buf0, row_ptr, cw, perm);
    for (int i = 1; i <= 8; ++i) {
        const unsigned short* src_b = (i & 1) ? buf0 : buf1;
        unsigned short* dst_b       = (i & 1) ? buf1 : buf0;
        prop_kernel<0, 1><<<pgrid, 256, 0, stream>>>(src_b, PSTRIDE, hb, dst_b, row_ptr, cw, perm);
    }
    prop_kernel<1, 0><<<pgrid, 256, 0, stream>>>(buf0, PSTRIDE, h, z, row_ptr, cw, perm);

    // ---- semantic attention (MFMA) ----
    hipMemsetAsync(wsum, 0, 3 * 4, stream);
    attn_kernel<<<2344, 256, 0, stream>>>(z, W1t, b1, w2, wsum);
    beta_kernel<<<1, 64, 0, stream>>>(wsum, beta);
    combine_kernel<<<(N_NODES * 32 + 255) / 256, 256, 0, stream>>>(
        (const float4*)z, beta, (float4*)out);
}

// Round 13
// 994.363 us; speedup vs baseline: 1.3005x; 1.3005x over previous
//
#include <hip/hip_runtime.h>
#include <math.h>

#define N_NODES 100000
#define N_EDGES 500000
#define N_PATHS 3
#define DIM 128
#define K_LAYERS 10
#define NBLK_PER_PATH ((N_NODES + 255) / 256)   // 391
#define PN (N_PATHS * N_NODES)                  // 300000
#define HRANGE 8192                             // LDS histogram bins (32 KB)
#define NRANGE ((N_NODES + HRANGE - 1) / HRANGE) // 13
#define BPG 16                                  // blocks per histogram group
#define ATTN_GRID 512

typedef __attribute__((ext_vector_type(8))) short bf16x8;
typedef __attribute__((ext_vector_type(4))) float f32x4;

__device__ __forceinline__ float bflo(unsigned u) { return __uint_as_float(u << 16); }
__device__ __forceinline__ float bfhi(unsigned u) { return __uint_as_float(u & 0xffff0000u); }

// ---------------- degree histograms via LDS privatization -----------------------
__global__ __launch_bounds__(256) void hist_kernel(const int* __restrict__ edges,
                                                   int* __restrict__ partial) {
    __shared__ int hist[HRANGE];
    int g = blockIdx.x / BPG;
    int b = blockIdx.x - g * BPG;
    int r = g % NRANGE;
    int pt = g / NRANGE;           // p*2 + t
    int p = pt >> 1, t = pt & 1;
    for (int i = threadIdx.x; i < HRANGE; i += 256) hist[i] = 0;
    __syncthreads();

    const int4* arr4 = (const int4*)(edges + ((size_t)p * 2 + t) * N_EDGES);
    const int n4 = N_EDGES / 4;
    const int stride = BPG * 256;
    int lo = r * HRANGE;

    int i4 = b * 256 + threadIdx.x;
    int4 cur = make_int4(-1, -1, -1, -1);
    if (i4 < n4) cur = arr4[i4];
    while (i4 < n4) {
        int ni = i4 + stride;
        int4 nxt = make_int4(-1, -1, -1, -1);
        if (ni < n4) nxt = arr4[ni];           // prefetch in flight during processing
        int v0 = cur.x - lo, v1 = cur.y - lo, v2 = cur.z - lo, v3 = cur.w - lo;
        if ((unsigned)v0 < HRANGE) atomicAdd(&hist[v0], 1);
        if ((unsigned)v1 < HRANGE) atomicAdd(&hist[v1], 1);
        if ((unsigned)v2 < HRANGE) atomicAdd(&hist[v2], 1);
        if ((unsigned)v3 < HRANGE) atomicAdd(&hist[v3], 1);
        cur = nxt;
        i4 = ni;
    }
    __syncthreads();
    int* outp = partial + ((size_t)g * BPG + b) * HRANGE;
    for (int i = threadIdx.x; i < HRANGE; i += 256) outp[i] = hist[i];
}

// ---------------- reduce partials -> norms + total in-degree ----------------
__global__ __launch_bounds__(256) void deg_reduce_kernel(const int* __restrict__ partial,
                                                         float* __restrict__ norm_s,
                                                         float* __restrict__ norm_d,
                                                         int* __restrict__ degD_tot) {
    int i = blockIdx.x * 256 + threadIdx.x;
    if (i >= PN) return;
    int p = i / N_NODES, n = i - p * N_NODES;
    int r = n / HRANGE, off = n - r * HRANGE;
    const int* ps = partial + (((size_t)(p * 2 + 0) * NRANGE + r) * BPG) * HRANGE + off;
    const int* pd = partial + (((size_t)(p * 2 + 1) * NRANGE + r) * BPG) * HRANGE + off;
    int sS = 0, sD = 0;
#pragma unroll
    for (int b = 0; b < BPG; ++b) {
        sS += ps[(size_t)b * HRANGE];
        sD += pd[(size_t)b * HRANGE];
    }
    norm_s[i] = 1.0f / sqrtf(fmaxf((float)sS, 1.0f));
    norm_d[i] = 1.0f / sqrtf(fmaxf((float)sD, 1.0f));
    degD_tot[i] = sD;
}

// ---------------- hierarchical scan: phase A - per-block sums ----------------
__global__ __launch_bounds__(256) void blocksum_kernel(const int* __restrict__ cnt,
                                                       int* __restrict__ bsum) {
    int b = blockIdx.x;
    int p = b / NBLK_PER_PATH;
    int lb = b - p * NBLK_PER_PATH;
    int idx = lb * 256 + threadIdx.x;
    int v = (idx < N_NODES) ? cnt[p * N_NODES + idx] : 0;
#pragma unroll
    for (int off = 32; off; off >>= 1) v += __shfl_xor(v, off);
    __shared__ int ws[4];
    if ((threadIdx.x & 63) == 0) ws[threadIdx.x >> 6] = v;
    __syncthreads();
    if (threadIdx.x == 0) bsum[b] = ws[0] + ws[1] + ws[2] + ws[3];
}

// ---------------- phase B - scan the 391 block sums per path --------
__global__ __launch_bounds__(512) void pscan_kernel(int* __restrict__ bsum) {
    __shared__ int s[512];
    int p = blockIdx.x;
    int t = threadIdx.x;
    int v = (t < NBLK_PER_PATH) ? bsum[p * NBLK_PER_PATH + t] : 0;
    s[t] = v;
    __syncthreads();
    for (int off = 1; off < 512; off <<= 1) {
        int x = s[t];
        int a = (t >= off) ? s[t - off] : 0;
        __syncthreads();
        s[t] = x + a;
        __syncthreads();
    }
    if (t < NBLK_PER_PATH) bsum[p * NBLK_PER_PATH + t] = s[t] - v;   // exclusive
}

// ---------------- phase C - block-local rescan + write row_ptr/cursor ----------
__global__ __launch_bounds__(256) void scan_write_kernel(const int* __restrict__ cnt,
                                                         const int* __restrict__ bsum,
                                                         int* __restrict__ row_ptr_all,
                                                         int* __restrict__ cursor_all) {
    __shared__ int s[256];
    int b = blockIdx.x;
    int p = b / NBLK_PER_PATH;
    int lb = b - p * NBLK_PER_PATH;
    int idx = lb * 256 + threadIdx.x;
    int t = threadIdx.x;
    int v = (idx < N_NODES) ? cnt[p * N_NODES + idx] : 0;
    s[t] = v;
    __syncthreads();
    for (int off = 1; off < 256; off <<= 1) {
        int x = s[t];
        int a = (t >= off) ? s[t - off] : 0;
        __syncthreads();
        s[t] = x + a;
        __syncthreads();
    }
    int excl = s[t] - v + bsum[b];
    if (idx < N_NODES) {
        row_ptr_all[p * (N_NODES + 1) + idx] = excl;
        cursor_all[p * N_NODES + idx] = excl;
        if (idx == N_NODES - 1)
            row_ptr_all[p * (N_NODES + 1) + N_NODES] = excl + v;
    }
}

// ---------------- fill CSR: col=src, weight=0.9*norm_s[src]*norm_d[dst] --------
__global__ __launch_bounds__(256) void fill_kernel(const int* __restrict__ edges,
                                                   const float* __restrict__ norm_s,
                                                   const float* __restrict__ norm_d,
                                                   int* __restrict__ cursor,
                                                   int2* __restrict__ cw) {
    int idx = blockIdx.x * 256 + threadIdx.x;
    if (idx < N_PATHS * N_EDGES) {
        int p = idx / N_EDGES;
        int e = idx - p * N_EDGES;
        const int* src = edges + (size_t)p * 2 * N_EDGES;
        const int* dst = src + N_EDGES;
        int s = src[e], d = dst[e];
        int pos = atomicAdd(&cursor[p * N_NODES + d], 1);
        float w = 0.9f * norm_s[p * N_NODES + s] * norm_d[p * N_NODES + d];
        cw[(size_t)p * N_EDGES + pos] = make_int2(s, __float_as_int(w));
    }
}

__device__ __forceinline__ unsigned bf16pack(float a, float b) {
    unsigned ua = __float_as_uint(a), ub = __float_as_uint(b);
    ua = (ua + 0x7fffu + ((ua >> 16) & 1)) >> 16;
    ub = (ub + 0x7fffu + ((ub >> 16) & 1)) >> 16;
    return ua | (ub << 16);
}

// ---------------- f32 -> bf16 cast of h (once) ----------------
__global__ __launch_bounds__(256) void cast_kernel(const float4* __restrict__ in,
                                                   ushort4* __restrict__ outp) {
    int idx = blockIdx.x * 256 + threadIdx.x;
    if (idx < N_NODES * DIM / 4) {
        float4 v = in[idx];
        ushort4 o;
        unsigned u;
        u = __float_as_uint(v.x); o.x = (unsigned short)((u + 0x7fff + ((u >> 16) & 1)) >> 16);
        u = __float_as_uint(v.y); o.y = (unsigned short)((u + 0x7fff + ((u >> 16) & 1)) >> 16);
        u = __float_as_uint(v.z); o.z = (unsigned short)((u + 0x7fff + ((u >> 16) & 1)) >> 16);
        u = __float_as_uint(v.w); o.w = (unsigned short)((u + 0x7fff + ((u >> 16) & 1)) >> 16);
        outp[idx] = o;
    }
}

// ---------------- W1^T bf16 (128x128, once) ----------------
__global__ __launch_bounds__(256) void w1t_kernel(const float* __restrict__ W1,
                                                  unsigned short* __restrict__ W1t) {
    int idx = blockIdx.x * 256 + threadIdx.x;
    if (idx < DIM * DIM) {
        int c = idx >> 7, k = idx & 127;     // W1t[c][k] = bf16(W1[k][c])
        unsigned u = __float_as_uint(W1[k * DIM + c]);
        W1t[idx] = (unsigned short)((u + 0x7fff + ((u >> 16) & 1)) >> 16);
    }
}

// ---------------- one APPNP layer, bf16 state, octet-wave: 8 nodes per wave ----
template <int OUT_F32, int H_BF16>
__global__ __launch_bounds__(256) void prop_kernel(const unsigned short* __restrict__ xin,
                                                   size_t in_stride,    // elems per path (0 = shared)
                                                   const void* __restrict__ anchor,
                                                   void* __restrict__ xout,
                                                   const int* __restrict__ row_ptr,
                                                   const int2* __restrict__ cw) {
    int wid  = threadIdx.x >> 6;
    int lane = threadIdx.x & 63;
    int oct  = lane >> 3;          // node slot 0..7
    int ol   = lane & 7;           // uint4 column (covers ol and ol+8)
    int nodeBase = blockIdx.x * 32 + wid * 8;    // wave-uniform; one path per wave
    int p  = nodeBase / N_NODES;
    int nb = nodeBase - p * N_NODES;
    const int*  rp   = row_ptr + p * (N_NODES + 1);
    const int2* cwp  = cw + (size_t)p * N_EDGES;
    const uint4* xin4 = (const uint4*)(xin + (size_t)p * in_stride);

    int rv = 0;
    if (lane < 9) rv = rp[nb + lane];
    int beg = __shfl(rv, oct);
    int end = __shfl(rv, oct + 1);
    int deg = end - beg;
    int myNode = nb + oct;
    int maxd = deg;
    maxd = max(maxd, __shfl_xor(maxd, 8));
    maxd = max(maxd, __shfl_xor(maxd, 16));
    maxd = max(maxd, __shfl_xor(maxd, 32));

    float a0 = 0.f, a1 = 0.f, a2 = 0.f, a3 = 0.f;
    float a4 = 0.f, a5 = 0.f, a6 = 0.f, a7 = 0.f;
    float a8 = 0.f, a9 = 0.f, a10 = 0.f, a11 = 0.f;
    float a12 = 0.f, a13 = 0.f, a14 = 0.f, a15 = 0.f;

    for (int base = 0; base < maxd; base += 8) {
        int2 e = make_int2(0, 0);
        if (base + ol < deg) e = cwp[beg + base + ol];   // 8 edge records per node
        int lim = maxd - base; if (lim > 8) lim = 8;
#pragma unroll 4
        for (int j = 0; j < lim; ++j) {
            int lsrc = (lane & 56) | j;
            int   c = __shfl(e.x, lsrc);
            float w = __int_as_float(__shfl(e.y, lsrc));
            if (base + j < deg) {      // oct-uniform exec mask
                uint4 v1 = xin4[(size_t)c * 16 + ol];
                uint4 v2 = xin4[(size_t)c * 16 + 8 + ol];
                a0  = fmaf(w, bflo(v1.x), a0);  a1  = fmaf(w, bfhi(v1.x), a1);
                a2  = fmaf(w, bflo(v1.y), a2);  a3  = fmaf(w, bfhi(v1.y), a3);
                a4  = fmaf(w, bflo(v1.z), a4);  a5  = fmaf(w, bfhi(v1.z), a5);
                a6  = fmaf(w, bflo(v1.w), a6);  a7  = fmaf(w, bfhi(v1.w), a7);
                a8  = fmaf(w, bflo(v2.x), a8);  a9  = fmaf(w, bfhi(v2.x), a9);
                a10 = fmaf(w, bflo(v2.y), a10); a11 = fmaf(w, bfhi(v2.y), a11);
                a12 = fmaf(w, bflo(v2.z), a12); a13 = fmaf(w, bfhi(v2.z), a13);
                a14 = fmaf(w, bflo(v2.w), a14); a15 = fmaf(w, bfhi(v2.w), a15);
            }
        }
    }

    if (H_BF16) {
        uint4 hv1 = ((const uint4*)anchor)[(size_t)myNode * 16 + ol];
        uint4 hv2 = ((const uint4*)anchor)[(size_t)myNode * 16 + 8 + ol];
        a0  += 0.1f * bflo(hv1.x); a1  += 0.1f * bfhi(hv1.x);
        a2  += 0.1f * bflo(hv1.y); a3  += 0.1f * bfhi(hv1.y);
        a4  += 0.1f * bflo(hv1.z); a5  += 0.1f * bfhi(hv1.z);
        a6  += 0.1f * bflo(hv1.w); a7  += 0.1f * bfhi(hv1.w);
        a8  += 0.1f * bflo(hv2.x); a9  += 0.1f * bfhi(hv2.x);
        a10 += 0.1f * bflo(hv2.y); a11 += 0.1f * bfhi(hv2.y);
        a12 += 0.1f * bflo(hv2.z); a13 += 0.1f * bfhi(hv2.z);
        a14 += 0.1f * bflo(hv2.w); a15 += 0.1f * bfhi(hv2.w);
    } else {
        const float4* h4 = (const float4*)anchor + (size_t)myNode * 32;
        float4 p0 = h4[ol * 2], p1 = h4[ol * 2 + 1];
        float4 p2 = h4[ol * 2 + 16], p3 = h4[ol * 2 + 17];
        a0  += 0.1f * p0.x; a1  += 0.1f * p0.y; a2  += 0.1f * p0.z; a3  += 0.1f * p0.w;
        a4  += 0.1f * p1.x; a5  += 0.1f * p1.y; a6  += 0.1f * p1.z; a7  += 0.1f * p1.w;
        a8  += 0.1f * p2.x; a9  += 0.1f * p2.y; a10 += 0.1f * p2.z; a11 += 0.1f * p2.w;
        a12 += 0.1f * p3.x; a13 += 0.1f * p3.y; a14 += 0.1f * p3.z; a15 += 0.1f * p3.w;
    }

    size_t row = (size_t)p * N_NODES + myNode;
    if (OUT_F32) {
        float4* zo = (float4*)xout + row * 32;
        zo[ol * 2]      = make_float4(a0, a1, a2, a3);
        zo[ol * 2 + 1]  = make_float4(a4, a5, a6, a7);
        zo[ol * 2 + 16] = make_float4(a8, a9, a10, a11);
        zo[ol * 2 + 17] = make_float4(a12, a13, a14, a15);
    } else {
        uint4 o1, o2;
        o1.x = bf16pack(a0, a1);   o1.y = bf16pack(a2, a3);
        o1.z = bf16pack(a4, a5);   o1.w = bf16pack(a6, a7);
        o2.x = bf16pack(a8, a9);   o2.y = bf16pack(a10, a11);
        o2.z = bf16pack(a12, a13); o2.w = bf16pack(a14, a15);
        ((uint4*)xout)[row * 16 + ol]     = o1;
        ((uint4*)xout)[row * 16 + 8 + ol] = o2;
    }
}

__device__ __forceinline__ float fast_tanh(float x) {
    float e = __expf(2.0f * x);
    return 1.0f - 2.0f / (e + 1.0f);   // == (e-1)/(e+1) == tanh(x)
}

// ---------------- attention logits via MFMA; per-block partials, NO atomics ----
__global__ __launch_bounds__(256) void attn_kernel(const float* __restrict__ z,
                                                   const unsigned short* __restrict__ W1t,
                                                   const float* __restrict__ b1,
                                                   const float* __restrict__ w2,
                                                   float* __restrict__ wpart) {
    const int wid  = threadIdx.x >> 6;
    const int lane = threadIdx.x & 63;
    const int c0   = lane & 15;
    const int kh   = lane >> 4;

    const bf16x8* w1t8 = (const bf16x8*)W1t;
    bf16x8 Bf[8][4];
#pragma unroll
    for (int nt = 0; nt < 8; ++nt)
#pragma unroll
        for (int ks = 0; ks < 4; ++ks)
            Bf[nt][ks] = w1t8[(nt * 16 + c0) * 16 + ks * 4 + kh];

    float b1v[8], w2v[8];
#pragma unroll
    for (int nt = 0; nt < 8; ++nt) {
        b1v[nt] = b1[nt * 16 + c0];
        w2v[nt] = w2[nt * 16 + c0];
    }

    float accP0 = 0.f, accP1 = 0.f, accP2 = 0.f;
    const int NTILES = N_PATHS * N_NODES / 16;   // 18750
    const int TPP    = N_NODES / 16;             // 6250
    const int stride = gridDim.x * 4;
    const float4* zf4 = (const float4*)z;

    for (int t = blockIdx.x * 4 + wid; t < NTILES; t += stride) {
        size_t rbase = ((size_t)t * 16 + c0) * 32 + kh * 2;
        bf16x8 Af[4];
#pragma unroll
        for (int ks = 0; ks < 4; ++ks) {
            float4 x0 = zf4[rbase + ks * 8];
            float4 x1 = zf4[rbase + ks * 8 + 1];
            union { uint4 u; bf16x8 v; } cv;
            cv.u.x = bf16pack(x0.x, x0.y);
            cv.u.y = bf16pack(x0.z, x0.w);
            cv.u.z = bf16pack(x1.x, x1.y);
            cv.u.w = bf16pack(x1.z, x1.w);
            Af[ks] = cv.v;
        }
        f32x4 acc[8];
#pragma unroll
        for (int nt = 0; nt < 8; ++nt) acc[nt] = (f32x4){0.f, 0.f, 0.f, 0.f};
#pragma unroll
        for (int nt = 0; nt < 8; ++nt)
#pragma unroll
            for (int ks = 0; ks < 4; ++ks)
                acc[nt] = __builtin_amdgcn_mfma_f32_16x16x32_bf16(Af[ks], Bf[nt][ks], acc[nt], 0, 0, 0);

        float psum = 0.f;
#pragma unroll
        for (int nt = 0; nt < 8; ++nt) {
            psum += fast_tanh(acc[nt][0] + b1v[nt]) * w2v[nt];
            psum += fast_tanh(acc[nt][1] + b1v[nt]) * w2v[nt];
            psum += fast_tanh(acc[nt][2] + b1v[nt]) * w2v[nt];
            psum += fast_tanh(acc[nt][3] + b1v[nt]) * w2v[nt];
        }
#pragma unroll
        for (int off = 32; off; off >>= 1) psum += __shfl_xor(psum, off);
        if (lane == 0) {
            int p = t / TPP;
            if (p == 0) accP0 += psum;
            else if (p == 1) accP1 += psum;
            else accP2 += psum;
        }
    }
    // block-level reduce (LDS), one plain store per path per block — zero atomics
    __shared__ float part[4][3];
    if (lane == 0) {
        part[wid][0] = accP0;
        part[wid][1] = accP1;
        part[wid][2] = accP2;
    }
    __syncthreads();
    if (threadIdx.x < 3) {
        wpart[blockIdx.x * 3 + threadIdx.x] =
            part[0][threadIdx.x] + part[1][threadIdx.x] +
            part[2][threadIdx.x] + part[3][threadIdx.x];
    }
}

// ---------------- reduce block partials -> beta = softmax(mean logits) ----------
__global__ __launch_bounds__(256) void beta_kernel(const float* __restrict__ wpart,
                                                   int nblk,
                                                   float* __restrict__ beta) {
    __shared__ float s0[256], s1[256], s2[256];
    float a0 = 0.f, a1 = 0.f, a2 = 0.f;
    for (int i = threadIdx.x; i < nblk; i += 256) {
        a0 += wpart[i * 3 + 0];
        a1 += wpart[i * 3 + 1];
        a2 += wpart[i * 3 + 2];
    }
    s0[threadIdx.x] = a0; s1[threadIdx.x] = a1; s2[threadIdx.x] = a2;
    __syncthreads();
    for (int off = 128; off; off >>= 1) {
        if (threadIdx.x < off) {
            s0[threadIdx.x] += s0[threadIdx.x + off];
            s1[threadIdx.x] += s1[threadIdx.x + off];
            s2[threadIdx.x] += s2[threadIdx.x + off];
        }
        __syncthreads();
    }
    if (threadIdx.x == 0) {
        float w0 = s0[0] * (1.0f / N_NODES);
        float w1 = s1[0] * (1.0f / N_NODES);
        float w2v = s2[0] * (1.0f / N_NODES);
        float m = fmaxf(w0, fmaxf(w1, w2v));
        float e0 = expf(w0 - m), e1 = expf(w1 - m), e2 = expf(w2v - m);
        float inv = 1.0f / (e0 + e1 + e2);
        beta[0] = e0 * inv;
        beta[1] = e1 * inv;
        beta[2] = e2 * inv;
    }
}

// ---------------- out[n,:] = sum_p beta[p] * z[p,n,:] ----------------
__global__ __launch_bounds__(256) void combine_kernel(const float4* __restrict__ z4,
                                                      const float* __restrict__ beta,
                                                      float4* __restrict__ out4) {
    size_t idx = (size_t)blockIdx.x * 256 + threadIdx.x;
    const size_t M = (size_t)N_NODES * 32;
    if (idx < M) {
        float b0 = beta[0], b1 = beta[1], b2 = beta[2];
        float4 a = z4[idx];
        float4 b = z4[M + idx];
        float4 c = z4[2 * M + idx];
        float4 o;
        o.x = b0 * a.x + b1 * b.x + b2 * c.x;
        o.y = b0 * a.y + b1 * b.y + b2 * c.y;
        o.z = b0 * a.z + b1 * b.z + b2 * c.z;
        o.w = b0 * a.w + b1 * b.w + b2 * c.w;
        out4[idx] = o;
    }
}

extern "C" void kernel_launch(void* const* d_in, const int* in_sizes, int n_in,
                              void* d_out, int out_size, void* d_ws, size_t ws_size,
                              hipStream_t stream) {
    const float* h     = (const float*)d_in[0];
    const int*   edges = (const int*)d_in[1];   // (3, 2, 500000) int32
    const float* W1    = (const float*)d_in[2];
    const float* b1    = (const float*)d_in[3];
    const float* w2    = (const float*)d_in[4];
    float* out = (float*)d_out;

    // ---- workspace carve ----
    char* ws = (char*)d_ws;
    float* z = (float*)ws;               ws += (size_t)N_PATHS * N_NODES * DIM * 4;  // 153.6 MB
    unsigned short* buf0 = (unsigned short*)ws; ws += (size_t)N_PATHS * N_NODES * DIM * 2;  // 76.8 MB
    int2* cw = (int2*)ws;                ws += (size_t)N_PATHS * N_EDGES * 8;        // 12 MB
    int* row_ptr = (int*)ws;             ws += (size_t)N_PATHS * (N_NODES + 1) * 4 + 12;
    float* norm_s = (float*)ws;          ws += (size_t)PN * 4;
    float* norm_d = (float*)ws;          ws += (size_t)PN * 4;
    int* bsum = (int*)ws;                ws += (size_t)N_PATHS * NBLK_PER_PATH * 4;
    float* wpart = (float*)ws;           ws += (size_t)ATTN_GRID * 3 * 4;
    float* beta = (float*)ws;            ws += 4 * 4;
    unsigned short* W1t = (unsigned short*)ws; ws += (size_t)DIM * DIM * 2;          // 32 KB
    // CSR-build temporaries inside buf0 (dead until prop layer 0 writes it):
    int* partial  = (int*)buf0;                               // 40.9 MB
    int* degD_tot = partial + (size_t)3 * 2 * NRANGE * BPG * HRANGE;  // 1.2 MB
    int* cursor   = degD_tot + PN;                            // 1.2 MB
    // aliases inside z (dead before layer 9 writes z):
    unsigned short* buf1 = (unsigned short*)z;                                   // 76.8 MB
    unsigned short* hb   = (unsigned short*)z + (size_t)N_PATHS * N_NODES * DIM; // 25.6 MB

    const size_t PSTRIDE = (size_t)N_NODES * DIM;   // per-path elems

    // ---- CSR build ----
    hist_kernel<<<3 * 2 * NRANGE * BPG, 256, 0, stream>>>(edges, partial);
    deg_reduce_kernel<<<(PN + 255) / 256, 256, 0, stream>>>(partial, norm_s, norm_d, degD_tot);
    blocksum_kernel<<<N_PATHS * NBLK_PER_PATH, 256, 0, stream>>>(degD_tot, bsum);
    pscan_kernel<<<N_PATHS, 512, 0, stream>>>(bsum);
    scan_write_kernel<<<N_PATHS * NBLK_PER_PATH, 256, 0, stream>>>(degD_tot, bsum, row_ptr, cursor);
    fill_kernel<<<(N_PATHS * N_EDGES + 255) / 256, 256, 0, stream>>>(edges, norm_s, norm_d, cursor, cw);

    // ---- one-time casts ----
    cast_kernel<<<(N_NODES * DIM / 4 + 255) / 256, 256, 0, stream>>>(
        (const float4*)h, (ushort4*)hb);
    w1t_kernel<<<(DIM * DIM + 255) / 256, 256, 0, stream>>>(W1, W1t);

    // ---- APPNP propagation: 10 fused layers over all 3 paths ----
    const int pgrid = PN / 32;   // 9375 blocks, 8 nodes/wave
    prop_kernel<0, 1><<<pgrid, 256, 0, stream>>>(hb, 0, hb, buf0, row_ptr, cw);
    for (int i = 1; i <= 8; ++i) {
        const unsigned short* src_b = (i & 1) ? buf0 : buf1;
        unsigned short* dst_b       = (i & 1) ? buf1 : buf0;
        prop_kernel<0, 1><<<pgrid, 256, 0, stream>>>(src_b, PSTRIDE, hb, dst_b, row_ptr, cw);
    }
    prop_kernel<1, 0><<<pgrid, 256, 0, stream>>>(buf0, PSTRIDE, h, z, row_ptr, cw);

    // ---- semantic attention (MFMA, atomic-free reduction) ----
    attn_kernel<<<ATTN_GRID, 256, 0, stream>>>(z, W1t, b1, w2, wpart);
    beta_kernel<<<1, 256, 0, stream>>>(wpart, ATTN_GRID, beta);
    combine_kernel<<<(N_NODES * 32 + 255) / 256, 256, 0, stream>>>(
        (const float4*)z, beta, (float4*)out);
}

// Round 14
// 993.491 us; speedup vs baseline: 1.3016x; 1.0009x over previous
//
#include <hip/hip_runtime.h>
#include <math.h>

#define N_NODES 100000
#define N_EDGES 500000
#define N_PATHS 3
#define DIM 128
#define K_LAYERS 10
#define NBLK_PER_PATH ((N_NODES + 255) / 256)   // 391
#define PN (N_PATHS * N_NODES)                  // 300000
#define HRANGE 8192                             // LDS histogram bins (32 KB)
#define NRANGE ((N_NODES + HRANGE - 1) / HRANGE) // 13
#define BPG 16                                  // blocks per histogram group
#define ATTN_GRID 1024

typedef __attribute__((ext_vector_type(8))) short bf16x8;
typedef __attribute__((ext_vector_type(4))) float f32x4;

__device__ __forceinline__ float bflo(unsigned u) { return __uint_as_float(u << 16); }
__device__ __forceinline__ float bfhi(unsigned u) { return __uint_as_float(u & 0xffff0000u); }

// ---------------- degree histograms via LDS privatization -----------------------
__global__ __launch_bounds__(256) void hist_kernel(const int* __restrict__ edges,
                                                   int* __restrict__ partial) {
    __shared__ int hist[HRANGE];
    int g = blockIdx.x / BPG;
    int b = blockIdx.x - g * BPG;
    int r = g % NRANGE;
    int pt = g / NRANGE;           // p*2 + t
    int p = pt >> 1, t = pt & 1;
    for (int i = threadIdx.x; i < HRANGE; i += 256) hist[i] = 0;
    __syncthreads();

    const int4* arr4 = (const int4*)(edges + ((size_t)p * 2 + t) * N_EDGES);
    const int n4 = N_EDGES / 4;
    const int stride = BPG * 256;
    int lo = r * HRANGE;

    int i4 = b * 256 + threadIdx.x;
    int4 cur = make_int4(-1, -1, -1, -1);
    if (i4 < n4) cur = arr4[i4];
    while (i4 < n4) {
        int ni = i4 + stride;
        int4 nxt = make_int4(-1, -1, -1, -1);
        if (ni < n4) nxt = arr4[ni];           // prefetch in flight during processing
        int v0 = cur.x - lo, v1 = cur.y - lo, v2 = cur.z - lo, v3 = cur.w - lo;
        if ((unsigned)v0 < HRANGE) atomicAdd(&hist[v0], 1);
        if ((unsigned)v1 < HRANGE) atomicAdd(&hist[v1], 1);
        if ((unsigned)v2 < HRANGE) atomicAdd(&hist[v2], 1);
        if ((unsigned)v3 < HRANGE) atomicAdd(&hist[v3], 1);
        cur = nxt;
        i4 = ni;
    }
    __syncthreads();
    int* outp = partial + ((size_t)g * BPG + b) * HRANGE;
    for (int i = threadIdx.x; i < HRANGE; i += 256) outp[i] = hist[i];
}

// ---------------- reduce partials -> norms + total in-degree ----------------
__global__ __launch_bounds__(256) void deg_reduce_kernel(const int* __restrict__ partial,
                                                         float* __restrict__ norm_s,
                                                         float* __restrict__ norm_d,
                                                         int* __restrict__ degD_tot) {
    int i = blockIdx.x * 256 + threadIdx.x;
    if (i >= PN) return;
    int p = i / N_NODES, n = i - p * N_NODES;
    int r = n / HRANGE, off = n - r * HRANGE;
    const int* ps = partial + (((size_t)(p * 2 + 0) * NRANGE + r) * BPG) * HRANGE + off;
    const int* pd = partial + (((size_t)(p * 2 + 1) * NRANGE + r) * BPG) * HRANGE + off;
    int sS = 0, sD = 0;
#pragma unroll
    for (int b = 0; b < BPG; ++b) {
        sS += ps[(size_t)b * HRANGE];
        sD += pd[(size_t)b * HRANGE];
    }
    norm_s[i] = 1.0f / sqrtf(fmaxf((float)sS, 1.0f));
    norm_d[i] = 1.0f / sqrtf(fmaxf((float)sD, 1.0f));
    degD_tot[i] = sD;
}

// ---------------- hierarchical scan: phase A - per-block sums ----------------
__global__ __launch_bounds__(256) void blocksum_kernel(const int* __restrict__ cnt,
                                                       int* __restrict__ bsum) {
    int b = blockIdx.x;
    int p = b / NBLK_PER_PATH;
    int lb = b - p * NBLK_PER_PATH;
    int idx = lb * 256 + threadIdx.x;
    int v = (idx < N_NODES) ? cnt[p * N_NODES + idx] : 0;
#pragma unroll
    for (int off = 32; off; off >>= 1) v += __shfl_xor(v, off);
    __shared__ int ws[4];
    if ((threadIdx.x & 63) == 0) ws[threadIdx.x >> 6] = v;
    __syncthreads();
    if (threadIdx.x == 0) bsum[b] = ws[0] + ws[1] + ws[2] + ws[3];
}

// ---------------- phase B - scan the 391 block sums per path --------
__global__ __launch_bounds__(512) void pscan_kernel(int* __restrict__ bsum) {
    __shared__ int s[512];
    int p = blockIdx.x;
    int t = threadIdx.x;
    int v = (t < NBLK_PER_PATH) ? bsum[p * NBLK_PER_PATH + t] : 0;
    s[t] = v;
    __syncthreads();
    for (int off = 1; off < 512; off <<= 1) {
        int x = s[t];
        int a = (t >= off) ? s[t - off] : 0;
        __syncthreads();
        s[t] = x + a;
        __syncthreads();
    }
    if (t < NBLK_PER_PATH) bsum[p * NBLK_PER_PATH + t] = s[t] - v;   // exclusive
}

// ---------------- phase C - block-local rescan + write row_ptr/cursor ----------
__global__ __launch_bounds__(256) void scan_write_kernel(const int* __restrict__ cnt,
                                                         const int* __restrict__ bsum,
                                                         int* __restrict__ row_ptr_all,
                                                         int* __restrict__ cursor_all) {
    __shared__ int s[256];
    int b = blockIdx.x;
    int p = b / NBLK_PER_PATH;
    int lb = b - p * NBLK_PER_PATH;
    int idx = lb * 256 + threadIdx.x;
    int t = threadIdx.x;
    int v = (idx < N_NODES) ? cnt[p * N_NODES + idx] : 0;
    s[t] = v;
    __syncthreads();
    for (int off = 1; off < 256; off <<= 1) {
        int x = s[t];
        int a = (t >= off) ? s[t - off] : 0;
        __syncthreads();
        s[t] = x + a;
        __syncthreads();
    }
    int excl = s[t] - v + bsum[b];
    if (idx < N_NODES) {
        row_ptr_all[p * (N_NODES + 1) + idx] = excl;
        cursor_all[p * N_NODES + idx] = excl;
        if (idx == N_NODES - 1)
            row_ptr_all[p * (N_NODES + 1) + N_NODES] = excl + v;
    }
}

// ---------------- fill CSR: col=src, weight=0.9*norm_s[src]*norm_d[dst] --------
__global__ __launch_bounds__(256) void fill_kernel(const int* __restrict__ edges,
                                                   const float* __restrict__ norm_s,
                                                   const float* __restrict__ norm_d,
                                                   int* __restrict__ cursor,
                                                   int2* __restrict__ cw) {
    int idx = blockIdx.x * 256 + threadIdx.x;
    if (idx < N_PATHS * N_EDGES) {
        int p = idx / N_EDGES;
        int e = idx - p * N_EDGES;
        const int* src = edges + (size_t)p * 2 * N_EDGES;
        const int* dst = src + N_EDGES;
        int s = src[e], d = dst[e];
        int pos = atomicAdd(&cursor[p * N_NODES + d], 1);
        float w = 0.9f * norm_s[p * N_NODES + s] * norm_d[p * N_NODES + d];
        cw[(size_t)p * N_EDGES + pos] = make_int2(s, __float_as_int(w));
    }
}

__device__ __forceinline__ unsigned bf16pack(float a, float b) {
    unsigned ua = __float_as_uint(a), ub = __float_as_uint(b);
    ua = (ua + 0x7fffu + ((ua >> 16) & 1)) >> 16;
    ub = (ub + 0x7fffu + ((ub >> 16) & 1)) >> 16;
    return ua | (ub << 16);
}

// ---------------- f32 -> bf16 cast of h (once) ----------------
__global__ __launch_bounds__(256) void cast_kernel(const float4* __restrict__ in,
                                                   ushort4* __restrict__ outp) {
    int idx = blockIdx.x * 256 + threadIdx.x;
    if (idx < N_NODES * DIM / 4) {
        float4 v = in[idx];
        ushort4 o;
        unsigned u;
        u = __float_as_uint(v.x); o.x = (unsigned short)((u + 0x7fff + ((u >> 16) & 1)) >> 16);
        u = __float_as_uint(v.y); o.y = (unsigned short)((u + 0x7fff + ((u >> 16) & 1)) >> 16);
        u = __float_as_uint(v.z); o.z = (unsigned short)((u + 0x7fff + ((u >> 16) & 1)) >> 16);
        u = __float_as_uint(v.w); o.w = (unsigned short)((u + 0x7fff + ((u >> 16) & 1)) >> 16);
        outp[idx] = o;
    }
}

// ---------------- W1^T bf16 (128x128, once) ----------------
__global__ __launch_bounds__(256) void w1t_kernel(const float* __restrict__ W1,
                                                  unsigned short* __restrict__ W1t) {
    int idx = blockIdx.x * 256 + threadIdx.x;
    if (idx < DIM * DIM) {
        int c = idx >> 7, k = idx & 127;     // W1t[c][k] = bf16(W1[k][c])
        unsigned u = __float_as_uint(W1[k * DIM + c]);
        W1t[idx] = (unsigned short)((u + 0x7fff + ((u >> 16) & 1)) >> 16);
    }
}

// ---------------- one APPNP layer, bf16 state, octet-wave: 8 nodes per wave ----
// Stores are wave-contiguous (shuffle remap): each store instruction covers a
// fully-contiguous 1KB block (4 complete 256B rows) -> no partial-sector writes.
// Memory layout is byte-identical to the gather layout (bit-identical results).
template <int OUT_F32, int H_BF16>
__global__ __launch_bounds__(256) void prop_kernel(const unsigned short* __restrict__ xin,
                                                   size_t in_stride,    // elems per path (0 = shared)
                                                   const void* __restrict__ anchor,
                                                   void* __restrict__ xout,
                                                   const int* __restrict__ row_ptr,
                                                   const int2* __restrict__ cw) {
    int wid  = threadIdx.x >> 6;
    int lane = threadIdx.x & 63;
    int oct  = lane >> 3;          // node slot 0..7
    int ol   = lane & 7;           // uint4 column (covers ol and ol+8)
    int nodeBase = blockIdx.x * 32 + wid * 8;    // wave-uniform; one path per wave
    int p  = nodeBase / N_NODES;
    int nb = nodeBase - p * N_NODES;
    const int*  rp   = row_ptr + p * (N_NODES + 1);
    const int2* cwp  = cw + (size_t)p * N_EDGES;
    const uint4* xin4 = (const uint4*)(xin + (size_t)p * in_stride);

    int rv = 0;
    if (lane < 9) rv = rp[nb + lane];
    int beg = __shfl(rv, oct);
    int end = __shfl(rv, oct + 1);
    int deg = end - beg;
    int myNode = nb + oct;
    int maxd = deg;
    maxd = max(maxd, __shfl_xor(maxd, 8));
    maxd = max(maxd, __shfl_xor(maxd, 16));
    maxd = max(maxd, __shfl_xor(maxd, 32));

    float a0 = 0.f, a1 = 0.f, a2 = 0.f, a3 = 0.f;
    float a4 = 0.f, a5 = 0.f, a6 = 0.f, a7 = 0.f;
    float a8 = 0.f, a9 = 0.f, a10 = 0.f, a11 = 0.f;
    float a12 = 0.f, a13 = 0.f, a14 = 0.f, a15 = 0.f;

    for (int base = 0; base < maxd; base += 8) {
        int2 e = make_int2(0, 0);
        if (base + ol < deg) e = cwp[beg + base + ol];   // 8 edge records per node
        int lim = maxd - base; if (lim > 8) lim = 8;
#pragma unroll 4
        for (int j = 0; j < lim; ++j) {
            int lsrc = (lane & 56) | j;
            int   c = __shfl(e.x, lsrc);
            float w = __int_as_float(__shfl(e.y, lsrc));
            if (base + j < deg) {      // oct-uniform exec mask
                uint4 v1 = xin4[(size_t)c * 16 + ol];
                uint4 v2 = xin4[(size_t)c * 16 + 8 + ol];
                a0  = fmaf(w, bflo(v1.x), a0);  a1  = fmaf(w, bfhi(v1.x), a1);
                a2  = fmaf(w, bflo(v1.y), a2);  a3  = fmaf(w, bfhi(v1.y), a3);
                a4  = fmaf(w, bflo(v1.z), a4);  a5  = fmaf(w, bfhi(v1.z), a5);
                a6  = fmaf(w, bflo(v1.w), a6);  a7  = fmaf(w, bfhi(v1.w), a7);
                a8  = fmaf(w, bflo(v2.x), a8);  a9  = fmaf(w, bfhi(v2.x), a9);
                a10 = fmaf(w, bflo(v2.y), a10); a11 = fmaf(w, bfhi(v2.y), a11);
                a12 = fmaf(w, bflo(v2.z), a12); a13 = fmaf(w, bfhi(v2.z), a13);
                a14 = fmaf(w, bflo(v2.w), a14); a15 = fmaf(w, bfhi(v2.w), a15);
            }
        }
    }

    if (H_BF16) {
        uint4 hv1 = ((const uint4*)anchor)[(size_t)myNode * 16 + ol];
        uint4 hv2 = ((const uint4*)anchor)[(size_t)myNode * 16 + 8 + ol];
        a0  += 0.1f * bflo(hv1.x); a1  += 0.1f * bfhi(hv1.x);
        a2  += 0.1f * bflo(hv1.y); a3  += 0.1f * bfhi(hv1.y);
        a4  += 0.1f * bflo(hv1.z); a5  += 0.1f * bfhi(hv1.z);
        a6  += 0.1f * bflo(hv1.w); a7  += 0.1f * bfhi(hv1.w);
        a8  += 0.1f * bflo(hv2.x); a9  += 0.1f * bfhi(hv2.x);
        a10 += 0.1f * bflo(hv2.y); a11 += 0.1f * bfhi(hv2.y);
        a12 += 0.1f * bflo(hv2.z); a13 += 0.1f * bfhi(hv2.z);
        a14 += 0.1f * bflo(hv2.w); a15 += 0.1f * bfhi(hv2.w);
    } else {
        const float4* h4 = (const float4*)anchor + (size_t)myNode * 32;
        float4 p0 = h4[ol * 2], p1 = h4[ol * 2 + 1];
        float4 p2 = h4[ol * 2 + 16], p3 = h4[ol * 2 + 17];
        a0  += 0.1f * p0.x; a1  += 0.1f * p0.y; a2  += 0.1f * p0.z; a3  += 0.1f * p0.w;
        a4  += 0.1f * p1.x; a5  += 0.1f * p1.y; a6  += 0.1f * p1.z; a7  += 0.1f * p1.w;
        a8  += 0.1f * p2.x; a9  += 0.1f * p2.y; a10 += 0.1f * p2.z; a11 += 0.1f * p2.w;
        a12 += 0.1f * p3.x; a13 += 0.1f * p3.y; a14 += 0.1f * p3.z; a15 += 0.1f * p3.w;
    }

    if (OUT_F32) {
        // wave-contiguous f32 store: 4 instrs x 1KB contiguous (8 rows x 512B)
        float4 f0 = make_float4(a0, a1, a2, a3);      // row chunk 2*ol
        float4 f1 = make_float4(a4, a5, a6, a7);      // 2*ol+1
        float4 f2 = make_float4(a8, a9, a10, a11);    // 2*ol+16
        float4 f3 = make_float4(a12, a13, a14, a15);  // 2*ol+17
        float4* zo = (float4*)xout + ((size_t)p * N_NODES + nb) * 32;
#pragma unroll
        for (int k = 0; k < 4; ++k) {
            int r2 = (k << 1) + (lane >> 5);          // row in block 0..7
            int c  = lane & 31;                       // float4 chunk in row
            int srcl = (r2 << 3) + ((c & 15) >> 1);
            float4 t0, t1, t2, t3;
            t0.x = __shfl(f0.x, srcl); t0.y = __shfl(f0.y, srcl);
            t0.z = __shfl(f0.z, srcl); t0.w = __shfl(f0.w, srcl);
            t1.x = __shfl(f1.x, srcl); t1.y = __shfl(f1.y, srcl);
            t1.z = __shfl(f1.z, srcl); t1.w = __shfl(f1.w, srcl);
            t2.x = __shfl(f2.x, srcl); t2.y = __shfl(f2.y, srcl);
            t2.z = __shfl(f2.z, srcl); t2.w = __shfl(f2.w, srcl);
            t3.x = __shfl(f3.x, srcl); t3.y = __shfl(f3.y, srcl);
            t3.z = __shfl(f3.z, srcl); t3.w = __shfl(f3.w, srcl);
            float4 v = (c & 16) ? ((c & 1) ? t3 : t2) : ((c & 1) ? t1 : t0);
            zo[k * 64 + lane] = v;
        }
    } else {
        uint4 o1, o2;
        o1.x = bf16pack(a0, a1);   o1.y = bf16pack(a2, a3);
        o1.z = bf16pack(a4, a5);   o1.w = bf16pack(a6, a7);
        o2.x = bf16pack(a8, a9);   o2.y = bf16pack(a10, a11);
        o2.z = bf16pack(a12, a13); o2.w = bf16pack(a14, a15);
        // wave-contiguous bf16 store: 2 instrs x 1KB contiguous (8 rows x 256B)
        int src = ((lane >> 4) << 3) | (lane & 7);    // source lane for rows 0..3
        bool hi = (lane & 8) != 0;                    // chunk >= 8 -> take o2
        uint4 pA1, pA2, pB1, pB2;
        pA1.x = __shfl(o1.x, src);      pA1.y = __shfl(o1.y, src);
        pA1.z = __shfl(o1.z, src);      pA1.w = __shfl(o1.w, src);
        pA2.x = __shfl(o2.x, src);      pA2.y = __shfl(o2.y, src);
        pA2.z = __shfl(o2.z, src);      pA2.w = __shfl(o2.w, src);
        pB1.x = __shfl(o1.x, src + 32); pB1.y = __shfl(o1.y, src + 32);
        pB1.z = __shfl(o1.z, src + 32); pB1.w = __shfl(o1.w, src + 32);
        pB2.x = __shfl(o2.x, src + 32); pB2.y = __shfl(o2.y, src + 32);
        pB2.z = __shfl(o2.z, src + 32); pB2.w = __shfl(o2.w, src + 32);
        uint4 vA = hi ? pA2 : pA1;
        uint4 vB = hi ? pB2 : pB1;
        size_t blk = ((size_t)p * N_NODES + nb) * 16;
        ((uint4*)xout)[blk + lane]      = vA;   // rows nb..nb+3, bytes 0..1023
        ((uint4*)xout)[blk + 64 + lane] = vB;   // rows nb+4..nb+7
    }
}

__device__ __forceinline__ float fast_tanh(float x) {
    float e = __expf(2.0f * x);
    return 1.0f - 2.0f / (e + 1.0f);   // == (e-1)/(e+1) == tanh(x)
}

// ---------------- attention logits via MFMA; per-block partials, NO atomics ----
__global__ __launch_bounds__(256) void attn_kernel(const float* __restrict__ z,
                                                   const unsigned short* __restrict__ W1t,
                                                   const float* __restrict__ b1,
                                                   const float* __restrict__ w2,
                                                   float* __restrict__ wpart) {
    const int wid  = threadIdx.x >> 6;
    const int lane = threadIdx.x & 63;
    const int c0   = lane & 15;
    const int kh   = lane >> 4;

    const bf16x8* w1t8 = (const bf16x8*)W1t;
    bf16x8 Bf[8][4];
#pragma unroll
    for (int nt = 0; nt < 8; ++nt)
#pragma unroll
        for (int ks = 0; ks < 4; ++ks)
            Bf[nt][ks] = w1t8[(nt * 16 + c0) * 16 + ks * 4 + kh];

    float b1v[8], w2v[8];
#pragma unroll
    for (int nt = 0; nt < 8; ++nt) {
        b1v[nt] = b1[nt * 16 + c0];
        w2v[nt] = w2[nt * 16 + c0];
    }

    float accP0 = 0.f, accP1 = 0.f, accP2 = 0.f;
    const int NTILES = N_PATHS * N_NODES / 16;   // 18750
    const int TPP    = N_NODES / 16;             // 6250
    const int stride = gridDim.x * 4;
    const float4* zf4 = (const float4*)z;

    for (int t = blockIdx.x * 4 + wid; t < NTILES; t += stride) {
        size_t rbase = ((size_t)t * 16 + c0) * 32 + kh * 2;
        bf16x8 Af[4];
#pragma unroll
        for (int ks = 0; ks < 4; ++ks) {
            float4 x0 = zf4[rbase + ks * 8];
            float4 x1 = zf4[rbase + ks * 8 + 1];
            union { uint4 u; bf16x8 v; } cv;
            cv.u.x = bf16pack(x0.x, x0.y);
            cv.u.y = bf16pack(x0.z, x0.w);
            cv.u.z = bf16pack(x1.x, x1.y);
            cv.u.w = bf16pack(x1.z, x1.w);
            Af[ks] = cv.v;
        }
        f32x4 acc[8];
#pragma unroll
        for (int nt = 0; nt < 8; ++nt) acc[nt] = (f32x4){0.f, 0.f, 0.f, 0.f};
#pragma unroll
        for (int nt = 0; nt < 8; ++nt)
#pragma unroll
            for (int ks = 0; ks < 4; ++ks)
                acc[nt] = __builtin_amdgcn_mfma_f32_16x16x32_bf16(Af[ks], Bf[nt][ks], acc[nt], 0, 0, 0);

        float psum = 0.f;
#pragma unroll
        for (int nt = 0; nt < 8; ++nt) {
            psum += fast_tanh(acc[nt][0] + b1v[nt]) * w2v[nt];
            psum += fast_tanh(acc[nt][1] + b1v[nt]) * w2v[nt];
            psum += fast_tanh(acc[nt][2] + b1v[nt]) * w2v[nt];
            psum += fast_tanh(acc[nt][3] + b1v[nt]) * w2v[nt];
        }
#pragma unroll
        for (int off = 32; off; off >>= 1) psum += __shfl_xor(psum, off);
        if (lane == 0) {
            int p = t / TPP;
            if (p == 0) accP0 += psum;
            else if (p == 1) accP1 += psum;
            else accP2 += psum;
        }
    }
    // block-level reduce (LDS), one plain store per path per block — zero atomics
    __shared__ float part[4][3];
    if (lane == 0) {
        part[wid][0] = accP0;
        part[wid][1] = accP1;
        part[wid][2] = accP2;
    }
    __syncthreads();
    if (threadIdx.x < 3) {
        wpart[blockIdx.x * 3 + threadIdx.x] =
            part[0][threadIdx.x] + part[1][threadIdx.x] +
            part[2][threadIdx.x] + part[3][threadIdx.x];
    }
}

// ---------------- reduce block partials -> beta = softmax(mean logits) ----------
__global__ __launch_bounds__(256) void beta_kernel(const float* __restrict__ wpart,
                                                   int nblk,
                                                   float* __restrict__ beta) {
    __shared__ float s0[256], s1[256], s2[256];
    float a0 = 0.f, a1 = 0.f, a2 = 0.f;
    for (int i = threadIdx.x; i < nblk; i += 256) {
        a0 += wpart[i * 3 + 0];
        a1 += wpart[i * 3 + 1];
        a2 += wpart[i * 3 + 2];
    }
    s0[threadIdx.x] = a0; s1[threadIdx.x] = a1; s2[threadIdx.x] = a2;
    __syncthreads();
    for (int off = 128; off; off >>= 1) {
        if (threadIdx.x < off) {
            s0[threadIdx.x] += s0[threadIdx.x + off];
            s1[threadIdx.x] += s1[threadIdx.x + off];
            s2[threadIdx.x] += s2[threadIdx.x + off];
        }
        __syncthreads();
    }
    if (threadIdx.x == 0) {
        float w0 = s0[0] * (1.0f / N_NODES);
        float w1 = s1[0] * (1.0f / N_NODES);
        float w2v = s2[0] * (1.0f / N_NODES);
        float m = fmaxf(w0, fmaxf(w1, w2v));
        float e0 = expf(w0 - m), e1 = expf(w1 - m), e2 = expf(w2v - m);
        float inv = 1.0f / (e0 + e1 + e2);
        beta[0] = e0 * inv;
        beta[1] = e1 * inv;
        beta[2] = e2 * inv;
    }
}

// ---------------- out[n,:] = sum_p beta[p] * z[p,n,:] ----------------
__global__ __launch_bounds__(256) void combine_kernel(const float4* __restrict__ z4,
                                                      const float* __restrict__ beta,
                                                      float4* __restrict__ out4) {
    size_t idx = (size_t)blockIdx.x * 256 + threadIdx.x;
    const size_t M = (size_t)N_NODES * 32;
    if (idx < M) {
        float b0 = beta[0], b1 = beta[1], b2 = beta[2];
        float4 a = z4[idx];
        float4 b = z4[M + idx];
        float4 c = z4[2 * M + idx];
        float4 o;
        o.x = b0 * a.x + b1 * b.x + b2 * c.x;
        o.y = b0 * a.y + b1 * b.y + b2 * c.y;
        o.z = b0 * a.z + b1 * b.z + b2 * c.z;
        o.w = b0 * a.w + b1 * b.w + b2 * c.w;
        out4[idx] = o;
    }
}

extern "C" void kernel_launch(void* const* d_in, const int* in_sizes, int n_in,
                              void* d_out, int out_size, void* d_ws, size_t ws_size,
                              hipStream_t stream) {
    const float* h     = (const float*)d_in[0];
    const int*   edges = (const int*)d_in[1];   // (3, 2, 500000) int32
    const float* W1    = (const float*)d_in[2];
    const float* b1    = (const float*)d_in[3];
    const float* w2    = (const float*)d_in[4];
    float* out = (float*)d_out;

    // ---- workspace carve ----
    char* ws = (char*)d_ws;
    float* z = (float*)ws;               ws += (size_t)N_PATHS * N_NODES * DIM * 4;  // 153.6 MB
    unsigned short* buf0 = (unsigned short*)ws; ws += (size_t)N_PATHS * N_NODES * DIM * 2;  // 76.8 MB
    int2* cw = (int2*)ws;                ws += (size_t)N_PATHS * N_EDGES * 8;        // 12 MB
    int* row_ptr = (int*)ws;             ws += (size_t)N_PATHS * (N_NODES + 1) * 4 + 12;
    float* norm_s = (float*)ws;          ws += (size_t)PN * 4;
    float* norm_d = (float*)ws;          ws += (size_t)PN * 4;
    int* bsum = (int*)ws;                ws += (size_t)N_PATHS * NBLK_PER_PATH * 4;
    float* wpart = (float*)ws;           ws += (size_t)ATTN_GRID * 3 * 4;
    float* beta = (float*)ws;            ws += 4 * 4;
    unsigned short* W1t = (unsigned short*)ws; ws += (size_t)DIM * DIM * 2;          // 32 KB
    // CSR-build temporaries inside buf0 (dead until prop layer 0 writes it):
    int* partial  = (int*)buf0;                               // 40.9 MB
    int* degD_tot = partial + (size_t)3 * 2 * NRANGE * BPG * HRANGE;  // 1.2 MB
    int* cursor   = degD_tot + PN;                            // 1.2 MB
    // aliases inside z (dead before layer 9 writes z):
    unsigned short* buf1 = (unsigned short*)z;                                   // 76.8 MB
    unsigned short* hb   = (unsigned short*)z + (size_t)N_PATHS * N_NODES * DIM; // 25.6 MB

    const size_t PSTRIDE = (size_t)N_NODES * DIM;   // per-path elems

    // ---- CSR build ----
    hist_kernel<<<3 * 2 * NRANGE * BPG, 256, 0, stream>>>(edges, partial);
    deg_reduce_kernel<<<(PN + 255) / 256, 256, 0, stream>>>(partial, norm_s, norm_d, degD_tot);
    blocksum_kernel<<<N_PATHS * NBLK_PER_PATH, 256, 0, stream>>>(degD_tot, bsum);
    pscan_kernel<<<N_PATHS, 512, 0, stream>>>(bsum);
    scan_write_kernel<<<N_PATHS * NBLK_PER_PATH, 256, 0, stream>>>(degD_tot, bsum, row_ptr, cursor);
    fill_kernel<<<(N_PATHS * N_EDGES + 255) / 256, 256, 0, stream>>>(edges, norm_s, norm_d, cursor, cw);

    // ---- one-time casts ----
    cast_kernel<<<(N_NODES * DIM / 4 + 255) / 256, 256, 0, stream>>>(
        (const float4*)h, (ushort4*)hb);
    w1t_kernel<<<(DIM * DIM + 255) / 256, 256, 0, stream>>>(W1, W1t);

    // ---- APPNP propagation: 10 fused layers over all 3 paths ----
    const int pgrid = PN / 32;   // 9375 blocks, 8 nodes/wave
    prop_kernel<0, 1><<<pgrid, 256, 0, stream>>>(hb, 0, hb, buf0, row_ptr, cw);
    for (int i = 1; i <= 8; ++i) {
        const unsigned short* src_b = (i & 1) ? buf0 : buf1;
        unsigned short* dst_b       = (i & 1) ? buf1 : buf0;
        prop_kernel<0, 1><<<pgrid, 256, 0, stream>>>(src_b, PSTRIDE, hb, dst_b, row_ptr, cw);
    }
    prop_kernel<1, 0><<<pgrid, 256, 0, stream>>>(buf0, PSTRIDE, h, z, row_ptr, cw);

    // ---- semantic attention (MFMA, atomic-free reduction) ----
    attn_kernel<<<ATTN_GRID, 256, 0, stream>>>(z, W1t, b1, w2, wpart);
    beta_kernel<<<1, 256, 0, stream>>>(wpart, ATTN_GRID, beta);
    combine_kernel<<<(N_NODES * 32 + 255) / 256, 256, 0, stream>>>(
        (const float4*)z, beta, (float4*)out);
}